// Round 21
// baseline (484.164 us; speedup 1.0000x reference)
//
#include <hip/hip_runtime.h>
#include <hip/hip_bf16.h>

#define M_TOTAL (32 * 64 * 64)   // 131072 rows
#define CDIM 256
#define HDIM 1024

typedef float  floatx4 __attribute__((ext_vector_type(4)));
typedef short  short8  __attribute__((ext_vector_type(8)));

// ---------------------------------------------------------------------------
// frag_pack: convert fp32 weight [K][N] (row-major) into fragment-major bf16:
//   dst16B[g][kk][lane] = { src[kk*32 + (lane>>4)*8 + e][g*16 + (lane&15)] }
// so one wave's B-fragment (64 lanes x 16B) is one CONTIGUOUS 1KB block.
// ---------------------------------------------------------------------------
__global__ __launch_bounds__(256) void frag_pack(
    const float* __restrict__ src, __hip_bfloat16* __restrict__ dst,
    int K, int N)
{
    const int idx  = blockIdx.x * 256 + threadIdx.x;   // one 16B frag / thread
    const int lane = idx & 63;
    const int nkk  = K >> 5;
    const int kk   = (idx >> 6) % nkk;
    const int g    = idx / (nkk << 6);
    const int col  = g * 16 + (lane & 15);
    const int k0   = kk * 32 + (lane >> 4) * 8;
    union { short8 v; __hip_bfloat16 h[8]; } p;
#pragma unroll
    for (int e = 0; e < 8; ++e)
        p.h[e] = __float2bfloat16(src[(long)(k0 + e) * N + col]);
    ((short8*)dst)[idx] = p.v;
}

// fast GELU (tanh form), max dev vs erf-GELU ~1e-3 (validated R2-R20)
__device__ __forceinline__ float gelu_fast(float v)
{
    const float t = v * __builtin_fmaf(v * v, 0.044715f, 1.0f);
    const float e = __expf(t * -1.5957691216f);
    return v * __builtin_amdgcn_rcpf(1.0f + e);
}

// ---------------------------------------------------------------------------
// Fused Swin block, R21: PRODUCER/CONSUMER WAVE SPECIALIZATION.
//   R18-R20 evidence: the per-chunk serial chain FC1->bar->GELU->bar->FC2 is
//   the wall (325us ~ sum of phases; no single roofline near).  Split roles:
//     waves 0-3 (producers): FC1(c) + GELU -> Hs[c&1]     (64 MFMA/chunk)
//     waves 4-7 (consumers): FC2(c-1) from Hs[(c-1)&1]    (64 MFMA/chunk)
//   run CONCURRENTLY between barriers -> per-chunk critical path becomes
//   max(FC1+GELU, FC2), deterministic in-block overlap (not cross-block luck).
//   Skewed loop c=0..8, ONE barrier per iteration (uniform across the
//   divergent roles).  Hs double-buffered: producer writes Hs[c&1], consumer
//   reads Hs[(c-1)&1] — disjoint, race-free under the per-iteration barrier.
//   512 thr, M-tile 64, chunk 128, frag-major weights (R16 win), fp32 xnbuf,
//   LDS = As 32KB + Hs 2x16KB = 64KB -> 2 blocks/CU.  launch_bounds(512,4)
//   (R18's proven operating point; (512,2)/(512,6) allocator pathologies).
// Frag conventions verified R1-R20: A/B k-map slot=kf*4+fq, elem k&7,
// row/col=fr; C/D col=lane&15, row=(lane>>4)*4+reg.
// ---------------------------------------------------------------------------
__global__ __launch_bounds__(512, 4) void swin_fused(
    const float* __restrict__ x,
    const float* __restrict__ ln1g, const float* __restrict__ ln1b,
    const float* __restrict__ ln2g, const float* __restrict__ ln2b,
    const short8* __restrict__ w1f, const float* __restrict__ fb1,
    const short8* __restrict__ w2f, const float* __restrict__ fb2,
    float* __restrict__ xnbuf, float* __restrict__ out)
{
    __shared__ __align__(16) __hip_bfloat16 As[16384];      // 32 KB [slot32][row64][8]
    __shared__ __align__(16) __hip_bfloat16 Hs[2][8192];    // 2 x 16 KB

    const int  tid = threadIdx.x;
    const long m0  = (long)blockIdx.x * 64;

    // ---------------- LN phase: 8 threads per row (all 512 thr) -----------
    {
        const int row  = tid >> 3;        // 0..63
        const int part = tid & 7;         // 32-element segment
        const float* xr = x + (m0 + row) * CDIM + part * 32;

        float4 v[8];
        float s = 0.f, sq = 0.f;
#pragma unroll
        for (int i = 0; i < 8; ++i) {
            v[i] = ((const float4*)xr)[i];
            s  += v[i].x + v[i].y + v[i].z + v[i].w;
            sq += v[i].x*v[i].x + v[i].y*v[i].y + v[i].z*v[i].z + v[i].w*v[i].w;
        }
        s  += __shfl_xor(s, 1);  s  += __shfl_xor(s, 2);  s  += __shfl_xor(s, 4);
        sq += __shfl_xor(sq, 1); sq += __shfl_xor(sq, 2); sq += __shfl_xor(sq, 4);
        const float mu = s * (1.f / CDIM);
        const float rs = rsqrtf(sq * (1.f / CDIM) - mu * mu + 1e-5f);

        float s2 = 0.f, q2 = 0.f;
        float* xnp = xnbuf + (m0 + row) * CDIM + part * 32;
#pragma unroll
        for (int i = 0; i < 8; ++i) {
            const float4 G = ((const float4*)(ln1g + part * 32))[i];
            const float4 B = ((const float4*)(ln1b + part * 32))[i];
            v[i].x += (v[i].x - mu) * rs * G.x + B.x;
            v[i].y += (v[i].y - mu) * rs * G.y + B.y;
            v[i].z += (v[i].z - mu) * rs * G.z + B.z;
            v[i].w += (v[i].w - mu) * rs * G.w + B.w;
            s2 += v[i].x + v[i].y + v[i].z + v[i].w;
            q2 += v[i].x*v[i].x + v[i].y*v[i].y + v[i].z*v[i].z + v[i].w*v[i].w;
            ((float4*)xnp)[i] = v[i];
        }
        s2 += __shfl_xor(s2, 1); s2 += __shfl_xor(s2, 2); s2 += __shfl_xor(s2, 4);
        q2 += __shfl_xor(q2, 1); q2 += __shfl_xor(q2, 2); q2 += __shfl_xor(q2, 4);
        const float mu2 = s2 * (1.f / CDIM);
        const float rs2 = rsqrtf(q2 * (1.f / CDIM) - mu2 * mu2 + 1e-5f);

        // ln2 -> As fragment layout: slot=(k>>5)*4+((k>>3)&3), elem k&7
#pragma unroll
        for (int i = 0; i < 8; ++i) {
            const int col0 = part * 32 + i * 4;
            const float4 G = ((const float4*)(ln2g + part * 32))[i];
            const float4 B = ((const float4*)(ln2b + part * 32))[i];
            union { ushort4 u; __hip_bfloat16 h[4]; } p;
            p.h[0] = __float2bfloat16((v[i].x - mu2) * rs2 * G.x + B.x);
            p.h[1] = __float2bfloat16((v[i].y - mu2) * rs2 * G.y + B.y);
            p.h[2] = __float2bfloat16((v[i].z - mu2) * rs2 * G.z + B.z);
            p.h[3] = __float2bfloat16((v[i].w - mu2) * rs2 * G.w + B.w);
            const int idx16 = ((col0 >> 5) * 4 + ((col0 >> 3) & 3)) * 64 + row;
            *(ushort4*)(As + idx16 * 8 + (col0 & 7)) = p.u;
        }
    }
    __syncthreads();

    // ---------------- MLP phase: producer/consumer pipeline ---------------
    const int wave = tid >> 6;          // 0..7
    const int lane = tid & 63;
    const int fr = lane & 15, fq = lane >> 4;
    const bool producer = (wave < 4);
    const int  pw = wave;               // producer col-group 0..3 (128 chunk cols)
    const int  cw = wave - 4;           // consumer col-group 0..3 (256 out cols)

    floatx4 acc2[4][4] = {};            // consumers: 64 rows x 64 out-cols

    float fb2w[4];
#pragma unroll
    for (int nf = 0; nf < 4; ++nf)
        fb2w[nf] = fb2[((cw < 0 ? 0 : cw) * 64 + nf * 16 + fr) & 255];

#pragma unroll 1
    for (int c = 0; c <= 8; ++c) {
        if (producer) {
            if (c < 8) {
                // ---- FC1(c): rows 0..63 (mf=4), cols pw*32+nf*16 (nf<2) ----
                floatx4 acc1[4][2];
#pragma unroll
                for (int mf = 0; mf < 4; ++mf)
#pragma unroll
                    for (int nf = 0; nf < 2; ++nf)
                        acc1[mf][nf] = (floatx4){0.f, 0.f, 0.f, 0.f};
#pragma unroll
                for (int kf = 0; kf < 8; ++kf) {
                    short8 b[2];
#pragma unroll
                    for (int nf = 0; nf < 2; ++nf)
                        b[nf] = w1f[((c * 8 + pw * 2 + nf) * 8 + kf) * 64 + lane];
                    short8 a[4];
#pragma unroll
                    for (int mf = 0; mf < 4; ++mf)
                        a[mf] = *(const short8*)(
                            As + ((kf * 4 + fq) * 64 + mf * 16 + fr) * 8);
#pragma unroll
                    for (int mf = 0; mf < 4; ++mf)
#pragma unroll
                        for (int nf = 0; nf < 2; ++nf)
                            acc1[mf][nf] = __builtin_amdgcn_mfma_f32_16x16x32_bf16(
                                a[mf], b[nf], acc1[mf][nf], 0, 0, 0);
                }
                // ---- GELU + bias -> Hs[c&1] ----
                __hip_bfloat16* hb = Hs[c & 1];
#pragma unroll
                for (int nf = 0; nf < 2; ++nf) {
                    const int col = pw * 32 + nf * 16 + fr;      // 0..127
                    const float bb1 = fb1[c * 128 + col];
                    __hip_bfloat16* hp =
                        hb + (((col >> 5) * 4 + ((col >> 3) & 3)) * 64) * 8 + (col & 7);
#pragma unroll
                    for (int mf = 0; mf < 4; ++mf)
#pragma unroll
                        for (int j = 0; j < 4; ++j) {
                            const int row = mf * 16 + fq * 4 + j;
                            hp[row * 8] =
                                __float2bfloat16(gelu_fast(acc1[mf][nf][j] + bb1));
                        }
                }
            }
        } else {
            if (c >= 1) {
                // ---- FC2(c-1): rows 0..63 (mf=4), cols cw*64+nf*16 (nf<4) --
                const int cc = c - 1;
                const __hip_bfloat16* hb = Hs[cc & 1];
#pragma unroll
                for (int kf = 0; kf < 4; ++kf) {
                    short8 bw[4];
#pragma unroll
                    for (int nf = 0; nf < 4; ++nf)
                        bw[nf] = w2f[((cw * 4 + nf) * 32 + cc * 4 + kf) * 64 + lane];
                    short8 ha[4];
#pragma unroll
                    for (int mf = 0; mf < 4; ++mf)
                        ha[mf] = *(const short8*)(
                            hb + ((kf * 4 + fq) * 64 + mf * 16 + fr) * 8);
#pragma unroll
                    for (int mf = 0; mf < 4; ++mf)
#pragma unroll
                        for (int nf = 0; nf < 4; ++nf)
                            acc2[mf][nf] = __builtin_amdgcn_mfma_f32_16x16x32_bf16(
                                ha[mf], bw[nf], acc2[mf][nf], 0, 0, 0);
                }
            }
        }
        __syncthreads();
    }

    // ---------------- epilogue (consumers only): out = acc2 + b2 + xn -----
    if (!producer) {
#pragma unroll
        for (int nf = 0; nf < 4; ++nf) {
            const int oc = cw * 64 + nf * 16 + fr;
#pragma unroll
            for (int mf = 0; mf < 4; ++mf)
#pragma unroll
                for (int j = 0; j < 4; ++j) {
                    const long row = m0 + mf * 16 + fq * 4 + j;
                    out[row * CDIM + oc] = acc2[mf][nf][j] + fb2w[nf]
                                         + xnbuf[row * CDIM + oc];
                }
        }
    }
}

// ---------------------------------------------------------------------------
extern "C" void kernel_launch(void* const* d_in, const int* in_sizes, int n_in,
                              void* d_out, int out_size, void* d_ws, size_t ws_size,
                              hipStream_t stream)
{
    const float* x    = (const float*)d_in[0];
    const float* ln1g = (const float*)d_in[1];
    const float* ln1b = (const float*)d_in[2];
    const float* ln2g = (const float*)d_in[3];
    const float* ln2b = (const float*)d_in[4];
    const float* w1   = (const float*)d_in[5];
    const float* b1   = (const float*)d_in[6];
    const float* w2   = (const float*)d_in[7];
    const float* b2   = (const float*)d_in[8];
    float* out = (float*)d_out;

    // workspace
    char* ws = (char*)d_ws;
    float*          xnbuf = (float*)ws;                           // 134,217,728 B
    __hip_bfloat16* w1fb  = (__hip_bfloat16*)(ws + 134217728);    //     524,288 B
    __hip_bfloat16* w2fb  = (__hip_bfloat16*)(ws + 134742016);    //     524,288 B

    // fragment-major weight packs:
    frag_pack<<<128, 256, 0, stream>>>(w1, w1fb, CDIM, HDIM);   // 64 cg x 8 kk
    frag_pack<<<128, 256, 0, stream>>>(w2, w2fb, HDIM, CDIM);   // 16 cg x 32 kk

    // fused block: 2048 blocks x 512 threads, 64 rows each, 2 blocks/CU
    swin_fused<<<M_TOTAL / 64, 512, 0, stream>>>(
        x, ln1g, ln1b, ln2g, ln2b,
        (const short8*)w1fb, b1, (const short8*)w2fb, b2, xnbuf, out);
}

// Round 22
// 320.897 us; speedup vs baseline: 1.5088x; 1.5088x over previous
//
#include <hip/hip_runtime.h>
#include <hip/hip_bf16.h>

#define M_TOTAL (32 * 64 * 64)   // 131072 rows
#define CDIM 256
#define HDIM 1024

typedef float  floatx4 __attribute__((ext_vector_type(4)));
typedef short  short8  __attribute__((ext_vector_type(8)));

// ---------------------------------------------------------------------------
// frag_pack: convert fp32 weight [K][N] (row-major) into fragment-major bf16:
//   dst16B[g][kk][lane] = { src[kk*32 + (lane>>4)*8 + e][g*16 + (lane&15)] }
// so one wave's B-fragment (64 lanes x 16B) is one CONTIGUOUS 1KB block.
// ---------------------------------------------------------------------------
__global__ __launch_bounds__(256) void frag_pack(
    const float* __restrict__ src, __hip_bfloat16* __restrict__ dst,
    int K, int N)
{
    const int idx  = blockIdx.x * 256 + threadIdx.x;   // one 16B frag / thread
    const int lane = idx & 63;
    const int nkk  = K >> 5;
    const int kk   = (idx >> 6) % nkk;
    const int g    = idx / (nkk << 6);
    const int col  = g * 16 + (lane & 15);
    const int k0   = kk * 32 + (lane >> 4) * 8;
    union { short8 v; __hip_bfloat16 h[8]; } p;
#pragma unroll
    for (int e = 0; e < 8; ++e)
        p.h[e] = __float2bfloat16(src[(long)(k0 + e) * N + col]);
    ((short8*)dst)[idx] = p.v;
}

// fast GELU (tanh form), max dev vs erf-GELU ~1e-3 (validated R2-R21)
__device__ __forceinline__ float gelu_fast(float v)
{
    const float t = v * __builtin_fmaf(v * v, 0.044715f, 1.0f);
    const float e = __expf(t * -1.5957691216f);
    return v * __builtin_amdgcn_rcpf(1.0f + e);
}

// ---------------------------------------------------------------------------
// Fused Swin block, R22 = EXACT REVERT TO R18 (best verified: 325us, 0.149).
//   Attention path is identity (window_reverse∘window_partition + canceling
//   rolls) -> block = x + LN1(x), then MLP with LN2 + residual, fully fused.
//   512 thr = 8 waves (1x8 col-groups), M-tile 64, hidden chunk 128.
//   LDS = As 32KB + single Hs 16KB = 48KB -> 3 blocks/CU = 6 waves/SIMD.
//   Fragment-major weights (R16: scatter->1KB burst, the one big win).
//   fp32 xnbuf residual.  2 barriers/chunk.  launch_bounds(512,4) = the only
//   allocator-stable point ((512,2): occ loss; (512,6): 40-VGPR spill storm).
// Levers tested and closed: occupancy (3blk max), bank-pad (worsens 3x),
// reg-prefetch (sink/spill x3), producer-consumer (union-spill).  The
// residual gap vs the 66us MFMA floor is the serial FC1->GELU->FC2 chain x
// JIT L2 weight latency — not addressable at HIP source on this compiler.
// Frag conventions verified R1-R21: A/B k-map slot=kf*4+fq, elem k&7,
// row/col=fr; C/D col=lane&15, row=(lane>>4)*4+reg.
// ---------------------------------------------------------------------------
__global__ __launch_bounds__(512, 4) void swin_fused(
    const float* __restrict__ x,
    const float* __restrict__ ln1g, const float* __restrict__ ln1b,
    const float* __restrict__ ln2g, const float* __restrict__ ln2b,
    const short8* __restrict__ w1f, const float* __restrict__ fb1,
    const short8* __restrict__ w2f, const float* __restrict__ fb2,
    float* __restrict__ xnbuf, float* __restrict__ out)
{
    __shared__ __align__(16) __hip_bfloat16 As[16384];   // 32 KB [slot32][row64][8]
    __shared__ __align__(16) __hip_bfloat16 Hs[8192];    // 16 KB [slot16][row64][8]

    const int  tid = threadIdx.x;
    const long m0  = (long)blockIdx.x * 64;

    // ---------------- LN phase: 8 threads per row ----------
    {
        const int row  = tid >> 3;        // 0..63
        const int part = tid & 7;         // 32-element segment
        const float* xr = x + (m0 + row) * CDIM + part * 32;

        float4 v[8];
        float s = 0.f, sq = 0.f;
#pragma unroll
        for (int i = 0; i < 8; ++i) {
            v[i] = ((const float4*)xr)[i];
            s  += v[i].x + v[i].y + v[i].z + v[i].w;
            sq += v[i].x*v[i].x + v[i].y*v[i].y + v[i].z*v[i].z + v[i].w*v[i].w;
        }
        s  += __shfl_xor(s, 1);  s  += __shfl_xor(s, 2);  s  += __shfl_xor(s, 4);
        sq += __shfl_xor(sq, 1); sq += __shfl_xor(sq, 2); sq += __shfl_xor(sq, 4);
        const float mu = s * (1.f / CDIM);
        const float rs = rsqrtf(sq * (1.f / CDIM) - mu * mu + 1e-5f);

        float s2 = 0.f, q2 = 0.f;
        float* xnp = xnbuf + (m0 + row) * CDIM + part * 32;
#pragma unroll
        for (int i = 0; i < 8; ++i) {
            const float4 G = ((const float4*)(ln1g + part * 32))[i];
            const float4 B = ((const float4*)(ln1b + part * 32))[i];
            v[i].x += (v[i].x - mu) * rs * G.x + B.x;
            v[i].y += (v[i].y - mu) * rs * G.y + B.y;
            v[i].z += (v[i].z - mu) * rs * G.z + B.z;
            v[i].w += (v[i].w - mu) * rs * G.w + B.w;
            s2 += v[i].x + v[i].y + v[i].z + v[i].w;
            q2 += v[i].x*v[i].x + v[i].y*v[i].y + v[i].z*v[i].z + v[i].w*v[i].w;
            ((float4*)xnp)[i] = v[i];
        }
        s2 += __shfl_xor(s2, 1); s2 += __shfl_xor(s2, 2); s2 += __shfl_xor(s2, 4);
        q2 += __shfl_xor(q2, 1); q2 += __shfl_xor(q2, 2); q2 += __shfl_xor(q2, 4);
        const float mu2 = s2 * (1.f / CDIM);
        const float rs2 = rsqrtf(q2 * (1.f / CDIM) - mu2 * mu2 + 1e-5f);

        // ln2 -> As fragment layout: slot=(k>>5)*4+((k>>3)&3), elem k&7
#pragma unroll
        for (int i = 0; i < 8; ++i) {
            const int col0 = part * 32 + i * 4;
            const float4 G = ((const float4*)(ln2g + part * 32))[i];
            const float4 B = ((const float4*)(ln2b + part * 32))[i];
            union { ushort4 u; __hip_bfloat16 h[4]; } p;
            p.h[0] = __float2bfloat16((v[i].x - mu2) * rs2 * G.x + B.x);
            p.h[1] = __float2bfloat16((v[i].y - mu2) * rs2 * G.y + B.y);
            p.h[2] = __float2bfloat16((v[i].z - mu2) * rs2 * G.z + B.z);
            p.h[3] = __float2bfloat16((v[i].w - mu2) * rs2 * G.w + B.w);
            const int idx16 = ((col0 >> 5) * 4 + ((col0 >> 3) & 3)) * 64 + row;
            *(ushort4*)(As + idx16 * 8 + (col0 & 7)) = p.u;
        }
    }
    __syncthreads();

    // ---------------- MLP phase (8 chunks of 128 hidden cols) -------------
    const int wn = tid >> 6;            // wave 0..7 = col-group
    const int lane = tid & 63;
    const int fr = lane & 15, fq = lane >> 4;

    floatx4 acc2[4][2] = {};            // 64 rows x 32 out-cols per wave

    float fb2w[2];
#pragma unroll
    for (int nf = 0; nf < 2; ++nf) fb2w[nf] = fb2[wn * 32 + nf * 16 + fr];

    // fragment-major bases:
    //   fc1 frag (chunk c, kf): w1f[((c*8 + wn)*8 + kf)*64 + lane]
    //   fc2 frag (chunk c, kf, nf): w2f[((wn*2+nf)*32 + c*4 + kf)*64 + lane]

#pragma unroll 2
    for (int c = 0; c < 8; ++c) {
        // ---- fc1: coalesced frag loads inside the MFMA loop ----
        const short8* p1 = w1f + ((c * 8 + wn) * 8) * 64 + lane;
        const float bb1 = fb1[c * 128 + wn * 16 + fr];

        floatx4 acc1[4];
#pragma unroll
        for (int mf = 0; mf < 4; ++mf) acc1[mf] = (floatx4){0.f, 0.f, 0.f, 0.f};
#pragma unroll
        for (int kf = 0; kf < 8; ++kf) {
            const short8 b = p1[kf * 64];
            short8 a[4];
#pragma unroll
            for (int mf = 0; mf < 4; ++mf)
                a[mf] = *(const short8*)(As + ((kf * 4 + fq) * 64 + mf * 16 + fr) * 8);
#pragma unroll
            for (int mf = 0; mf < 4; ++mf)
                acc1[mf] = __builtin_amdgcn_mfma_f32_16x16x32_bf16(
                    a[mf], b, acc1[mf], 0, 0, 0);
        }

        __syncthreads();   // all waves' FC2(c-1) Hs reads complete

        // ---- GELU + bias -> Hs (col = wn*16+fr) ----
        {
            const int col = wn * 16 + fr;
            __hip_bfloat16* hp =
                Hs + (((col >> 5) * 4 + ((col >> 3) & 3)) * 64) * 8 + (col & 7);
#pragma unroll
            for (int mf = 0; mf < 4; ++mf)
#pragma unroll
                for (int j = 0; j < 4; ++j) {
                    const int row = mf * 16 + fq * 4 + j;
                    hp[row * 8] = __float2bfloat16(gelu_fast(acc1[mf][j] + bb1));
                }
        }
        __syncthreads();   // Hs ready for all waves

        // ---- fc2 partial: coalesced frag loads, 8 MFMA/kf into acc2 ----
#pragma unroll
        for (int kf = 0; kf < 4; ++kf) {
            short8 bw[2];
#pragma unroll
            for (int nf = 0; nf < 2; ++nf)
                bw[nf] = w2f[((wn * 2 + nf) * 32 + c * 4 + kf) * 64 + lane];
            short8 ha[4];
#pragma unroll
            for (int mf = 0; mf < 4; ++mf)
                ha[mf] = *(const short8*)(Hs + ((kf * 4 + fq) * 64 + mf * 16 + fr) * 8);
#pragma unroll
            for (int mf = 0; mf < 4; ++mf)
#pragma unroll
                for (int nf = 0; nf < 2; ++nf)
                    acc2[mf][nf] = __builtin_amdgcn_mfma_f32_16x16x32_bf16(
                        ha[mf], bw[nf], acc2[mf][nf], 0, 0, 0);
        }
    }

    // ---------------- epilogue: out = acc2 + b2 + xn (fp32) ----------------
#pragma unroll
    for (int nf = 0; nf < 2; ++nf) {
        const int oc = wn * 32 + nf * 16 + fr;
#pragma unroll
        for (int mf = 0; mf < 4; ++mf)
#pragma unroll
            for (int j = 0; j < 4; ++j) {
                const long row = m0 + mf * 16 + fq * 4 + j;
                out[row * CDIM + oc] = acc2[mf][nf][j] + fb2w[nf]
                                     + xnbuf[row * CDIM + oc];
            }
    }
}

// ---------------------------------------------------------------------------
extern "C" void kernel_launch(void* const* d_in, const int* in_sizes, int n_in,
                              void* d_out, int out_size, void* d_ws, size_t ws_size,
                              hipStream_t stream)
{
    const float* x    = (const float*)d_in[0];
    const float* ln1g = (const float*)d_in[1];
    const float* ln1b = (const float*)d_in[2];
    const float* ln2g = (const float*)d_in[3];
    const float* ln2b = (const float*)d_in[4];
    const float* w1   = (const float*)d_in[5];
    const float* b1   = (const float*)d_in[6];
    const float* w2   = (const float*)d_in[7];
    const float* b2   = (const float*)d_in[8];
    float* out = (float*)d_out;

    // workspace
    char* ws = (char*)d_ws;
    float*          xnbuf = (float*)ws;                           // 134,217,728 B
    __hip_bfloat16* w1fb  = (__hip_bfloat16*)(ws + 134217728);    //     524,288 B
    __hip_bfloat16* w2fb  = (__hip_bfloat16*)(ws + 134742016);    //     524,288 B

    // fragment-major weight packs:
    frag_pack<<<128, 256, 0, stream>>>(w1, w1fb, CDIM, HDIM);   // 64 cg x 8 kk
    frag_pack<<<128, 256, 0, stream>>>(w2, w2fb, HDIM, CDIM);   // 16 cg x 32 kk

    // fused block: 2048 blocks x 512 threads, 64 rows each, 3 blocks/CU
    swin_fused<<<M_TOTAL / 64, 512, 0, stream>>>(
        x, ln1g, ln1b, ln2g, ln2b,
        (const short8*)w1fb, b1, (const short8*)w2fb, b2, xnbuf, out);
}